// Round 1
// baseline (234.349 us; speedup 1.0000x reference)
//
#include <hip/hip_runtime.h>
#include <hip/hip_bf16.h>
#include <stdint.h>

// Problem: 3x Bahdanau attention (p/c/h heads) -> averaged softmax weights -> weighted sum of sentence.
// S=8192, H2=1024, A=2048, E=768. All inputs fp32; output fp32 [1024].
// R2: 233.6us. k_gemm_e 71.5us latency-bound (MfmaUtil 13%, occ 14%, HBM 9.6%): 2-barrier BK=32 loop
//     exposes full global->LDS latency; effective len ~1900 rows -> only ~3 blocks/CU of TLP.
// R3: (a) GEMM: 3-buffer pipeline, 2 k-tiles in flight, counted s_waitcnt vmcnt(4) + raw s_barrier
//         (T3/T4-lite) -- never drain vmcnt to 0 in the main loop.
//     (b) k_prep phase 1 gated on length (skip cvt of masked rows); out-zeroing folded into k_prep.
//     (c) k_stats fused into k_out (redundant per-block stats from L2-hot e_arr); 6 -> 4 dispatches.

namespace {

constexpr int S = 8192;
constexpr int H = 1024;   // H2
constexpr int A = 2048;
constexpr int E = 768;

typedef __bf16 bf16x8 __attribute__((ext_vector_type(8)));
typedef float f32x4 __attribute__((ext_vector_type(4)));

__device__ __forceinline__ void gl_lds16(const void* g, void* l) {
  __builtin_amdgcn_global_load_lds(
      (const __attribute__((address_space(1))) void*)g,
      (__attribute__((address_space(3))) void*)l, 16, 0, 0);
}

// ---------- merged prep ----------
// [0,4096)      cvt sentence->bf16 (only rows < round_up(len,128))
// [4096,5632)   transpose W_sent fp32 [H][A] -> bf16 [A][H]
// [5632,6208)   ctxb[head][a] = ctx @ W_ctx + b_s + b_c  (atomic partials over E-chunks)
// 6208          zero out[] (replaces a memset dispatch)
__global__ __launch_bounds__(256)
void k_prep(const float* __restrict__ sentence, __bf16* __restrict__ sentB,
            const float* __restrict__ Wp, const float* __restrict__ Wc_s,
            const float* __restrict__ Wh, __bf16* __restrict__ WtB,
            const float* __restrict__ ctx_p, const float* __restrict__ ctx_c,
            const float* __restrict__ ctx_h,
            const float* __restrict__ Wcx_p, const float* __restrict__ Wcx_c,
            const float* __restrict__ Wcx_h,
            const float* __restrict__ bs_p, const float* __restrict__ bs_c,
            const float* __restrict__ bs_h,
            const float* __restrict__ bc_p, const float* __restrict__ bc_c,
            const float* __restrict__ bc_h,
            float* __restrict__ ctxb,
            const int* __restrict__ length, float* __restrict__ out, int n_out) {
  __shared__ float tile[64][65];
  int b = blockIdx.x;
  int t = threadIdx.x;

  if (b < 4096) {
    // ---- phase 1: sentence fp32 -> bf16, 8 elems/thread; 2 rows per block ----
    int len = min(max(length[0], 0), S);
    int lenp = (len + 127) & ~127;        // GEMM touches rows < round_up(len,128)
    if (b * 2 >= lenp) return;
    int g = b * 256 + t;
    const float4* s4 = (const float4*)sentence + (size_t)g * 2;
    float4 a = s4[0], c = s4[1];
    bf16x8 o;
    o[0] = (__bf16)a.x; o[1] = (__bf16)a.y; o[2] = (__bf16)a.z; o[3] = (__bf16)a.w;
    o[4] = (__bf16)c.x; o[5] = (__bf16)c.y; o[6] = (__bf16)c.z; o[7] = (__bf16)c.w;
    *((bf16x8*)sentB + g) = o;
  } else if (b < 5632) {
    // ---- phase 2: W_sent [H][A] fp32 -> Wt [A][H] bf16 ----
    int r = b - 4096;                 // 512 tiles per head
    int head = r >> 9; r &= 511;
    const float* W = head == 0 ? Wp : (head == 1 ? Wc_s : Wh);
    __bf16* dst = WtB + (size_t)head * A * H;
    int a0 = (r & 31) * 64;           // 32 a-tiles
    int k0 = (r >> 5) * 64;           // 16 k-tiles
#pragma unroll
    for (int i = 0; i < 16; ++i) {
      int idx = t + i * 256;
      int rr = idx >> 6, cc = idx & 63;
      tile[cc][rr] = W[(size_t)(k0 + rr) * A + a0 + cc];   // coalesced over cc
    }
    __syncthreads();
#pragma unroll
    for (int i = 0; i < 16; ++i) {
      int idx = t + i * 256;
      int al = idx >> 6, kl = idx & 63;
      dst[(size_t)(a0 + al) * H + k0 + kl] = (__bf16)tile[al][kl];  // coalesced over kl
    }
  } else if (b < 6208) {
    // ---- phase 3: ctxb[head][a] += chunk of ctx @ W_ctx (+bias in chunk 0) ----
    int r = b - 5632;                 // 192 blocks per head: 8 a-blocks x 24 e-chunks
    int head = r / 192; r %= 192;
    int ablk = r & 7;
    int echk = r >> 3;                // 24 chunks of 32
    const float* ctx = head == 0 ? ctx_p : (head == 1 ? ctx_c : ctx_h);
    const float* Wc  = head == 0 ? Wcx_p : (head == 1 ? Wcx_c : Wcx_h);
    int a = ablk * 256 + t;
    float s = 0.f;
    int e0 = echk * 32;
#pragma unroll 8
    for (int e = e0; e < e0 + 32; ++e) s = fmaf(ctx[e], Wc[(size_t)e * A + a], s);
    if (echk == 0) {
      const float* bs = head == 0 ? bs_p : (head == 1 ? bs_c : bs_h);
      const float* bc = head == 0 ? bc_p : (head == 1 ? bc_c : bc_h);
      s += bs[a] + bc[a];
    }
    atomicAdd(&ctxb[head * A + a], s);
  } else {
    // ---- phase 4: zero the output accumulator ----
    float4 z = {0.f, 0.f, 0.f, 0.f};
    for (int i = t; i * 4 < n_out; i += 256) ((float4*)out)[i] = z;
  }
}

// ---------- GEMM + fused tanh*v epilogue -> e[head][s] ----------
// 128x128 tile, BK=32, 3 LDS buffers, 2 k-tiles in flight via counted vmcnt.
// Per iter: {wait vmcnt(4); barrier; stage(t+2); ds_read(t); 16 MFMA}. The single-asm
// "s_waitcnt vmcnt(4)\n s_barrier" with memory clobber keeps compiler-scheduled ds_reads
// from hoisting above the barrier; lgkmcnt stays compiler-managed (no rule-#18 hazard).
__global__ __launch_bounds__(256)
void k_gemm_e(const __bf16* __restrict__ sentB, const __bf16* __restrict__ WtB,
              const float* __restrict__ ctxb,
              const float* __restrict__ v_p, const float* __restrict__ v_c,
              const float* __restrict__ v_h,
              const int* __restrict__ length, float* __restrict__ e_out) {
  int m0 = blockIdx.x * 128;
  int len = min(max(length[0], 0), S);
  if (m0 >= len) return;          // masked rows can never influence the softmax
  int n0 = blockIdx.y * 128;
  int head = blockIdx.z;
  const float* v  = head == 0 ? v_p : (head == 1 ? v_c : v_h);
  const __bf16* Wt = WtB + (size_t)head * A * H;
  const float* cb = ctxb + head * A;
  float* e_h = e_out + head * S;

  __shared__ __align__(16) __bf16 lsA[3 * 4096];   // 3 bufs x [128][32]
  __shared__ __align__(16) __bf16 lsB[3 * 4096];
  __shared__ float e_part[128];

  int tid = threadIdx.x;
  if (tid < 128) e_part[tid] = 0.f;

  int lane = tid & 63;
  int wave = tid >> 6;
  int wm = wave >> 1, wn = wave & 1;
  int quad = lane >> 4, l16 = lane & 15;

  f32x4 acc[4][4];
#pragma unroll
  for (int i = 0; i < 4; ++i)
#pragma unroll
    for (int j = 0; j < 4; ++j) acc[i][j] = (f32x4){0.f, 0.f, 0.f, 0.f};

  const __bf16* gA0 = sentB + (size_t)(m0 + (tid >> 2)) * H + ((tid & 3) * 8);
  const __bf16* gA1 = gA0 + (size_t)64 * H;
  const __bf16* gB0 = Wt + (size_t)(n0 + (tid >> 2)) * H + ((tid & 3) * 8);
  const __bf16* gB1 = gB0 + (size_t)64 * H;

#define STAGE(bufi, kk)                                           \
  do {                                                            \
    gl_lds16(gA0 + (kk), lsA + (bufi) * 4096 + tid * 8);          \
    gl_lds16(gA1 + (kk), lsA + (bufi) * 4096 + 2048 + tid * 8);   \
    gl_lds16(gB0 + (kk), lsB + (bufi) * 4096 + tid * 8);          \
    gl_lds16(gB1 + (kk), lsB + (bufi) * 4096 + 2048 + tid * 8);   \
  } while (0)

#define COMPUTE(bufi)                                                                     \
  do {                                                                                    \
    bf16x8 af[4], bfv[4];                                                                 \
    _Pragma("unroll")                                                                     \
    for (int i = 0; i < 4; ++i) {                                                         \
      af[i]  = *(const bf16x8*)&lsA[(bufi) * 4096 + (wm * 64 + i * 16 + l16) * 32 + quad * 8]; \
      bfv[i] = *(const bf16x8*)&lsB[(bufi) * 4096 + (wn * 64 + i * 16 + l16) * 32 + quad * 8]; \
    }                                                                                     \
    _Pragma("unroll")                                                                     \
    for (int i = 0; i < 4; ++i)                                                           \
      _Pragma("unroll")                                                                   \
      for (int j = 0; j < 4; ++j)                                                         \
        acc[i][j] = __builtin_amdgcn_mfma_f32_16x16x32_bf16(af[i], bfv[j], acc[i][j], 0, 0, 0); \
  } while (0)

  // prologue: 2 tiles in flight
  STAGE(0, 0);
  STAGE(1, 32);
  int cur = 0, nxt = 2;
#pragma unroll 1
  for (int t = 0; t < 31; ++t) {
    // tile t complete across ALL waves (each wave waited its own oldest 4 before barrier);
    // tile t+1 stays in flight.
    asm volatile("s_waitcnt vmcnt(4)\n\ts_barrier" ::: "memory");
    if (t < 30) STAGE(nxt, (t + 2) * 32);
    COMPUTE(cur);
    cur = cur == 2 ? 0 : cur + 1;
    nxt = nxt == 2 ? 0 : nxt + 1;
  }
  asm volatile("s_waitcnt vmcnt(0)\n\ts_barrier" ::: "memory");
  COMPUTE(cur);   // tile 31

#undef STAGE
#undef COMPUTE

  float vj[4], cbj[4];
#pragma unroll
  for (int j = 0; j < 4; ++j) {
    int col = n0 + wn * 64 + j * 16 + l16;
    vj[j] = v[col];
    cbj[j] = cb[col];
  }
#pragma unroll
  for (int i = 0; i < 4; ++i) {
#pragma unroll
    for (int r = 0; r < 4; ++r) {
      float p = 0.f;
#pragma unroll
      for (int j = 0; j < 4; ++j) {
        float u = acc[i][j][r] + cbj[j];
        float ex = __expf(2.f * u);        // tanh = 1 - 2/(e^2x+1); inf-safe at both ends
        float th = 1.f - 2.f / (ex + 1.f);
        p = fmaf(th, vj[j], p);
      }
      p += __shfl_xor(p, 1);
      p += __shfl_xor(p, 2);
      p += __shfl_xor(p, 4);
      p += __shfl_xor(p, 8);
      if (l16 == 0) atomicAdd(&e_part[wm * 64 + i * 16 + quad * 4 + r], p);
    }
  }
  __syncthreads();
  if (tid < 128) atomicAdd(&e_h[m0 + tid], e_part[tid]);
}

// ---------- out[h] = sum_s w(s) * sentence[s][h]; softmax stats computed per block ----------
// Stats are redundant per block (e_arr is L2-resident, ~46KB re-read) but remove the k_stats
// dispatch + its dependency edge. 16 rows/block for 2x parallelism over R2.
__global__ void k_out(const float* __restrict__ sent, const float* __restrict__ e_arr,
                      const int* __restrict__ length, float* __restrict__ out) {
  int len = min(max(length[0], 0), S);
  int r0 = blockIdx.x * 16;
  if (r0 >= len) return;
  int tid = threadIdx.x;

  __shared__ float red[3][4];
  __shared__ float sstat[6];    // m0,s0,m1,s1,m2,s2
  __shared__ float wrow[16];

  // pass 1: per-head max over s < len
#pragma unroll
  for (int h = 0; h < 3; ++h) {
    const float* e_h = e_arr + h * S;
    float m = -3.4e38f;
    for (int s = tid; s < len; s += 256) m = fmaxf(m, e_h[s]);
#pragma unroll
    for (int o = 32; o >= 1; o >>= 1) m = fmaxf(m, __shfl_xor(m, o));
    if ((tid & 63) == 0) red[h][tid >> 6] = m;
  }
  __syncthreads();
  if (tid < 3) sstat[tid * 2] = fmaxf(fmaxf(red[tid][0], red[tid][1]),
                                      fmaxf(red[tid][2], red[tid][3]));
  __syncthreads();
  // pass 2: per-head sum of exp
#pragma unroll
  for (int h = 0; h < 3; ++h) {
    const float* e_h = e_arr + h * S;
    float mm = sstat[h * 2];
    float ss = 0.f;
    for (int s = tid; s < len; s += 256) ss += __expf(e_h[s] - mm);
#pragma unroll
    for (int o = 32; o >= 1; o >>= 1) ss += __shfl_xor(ss, o);
    if ((tid & 63) == 0) red[h][tid >> 6] = ss;
  }
  __syncthreads();
  if (tid < 3) sstat[tid * 2 + 1] = red[tid][0] + red[tid][1] + red[tid][2] + red[tid][3];
  __syncthreads();

  // fused weights for this block's rows (computed once, not per-thread)
  if (tid < 16 && r0 + tid < len) {
    int r = r0 + tid;
    wrow[tid] = (__expf(e_arr[r] - sstat[0]) / sstat[1] +
                 __expf(e_arr[S + r] - sstat[2]) / sstat[3] +
                 __expf(e_arr[2 * S + r] - sstat[4]) / sstat[5]) * (1.f / 3.f);
  }
  __syncthreads();

  int col = tid * 4;
  int rend = min(r0 + 16, len);
  float4 acc = {0.f, 0.f, 0.f, 0.f};
  for (int r = r0; r < rend; ++r) {
    float w = wrow[r - r0];
    float4 x = *(const float4*)(sent + (size_t)r * H + col);
    acc.x = fmaf(w, x.x, acc.x);
    acc.y = fmaf(w, x.y, acc.y);
    acc.z = fmaf(w, x.z, acc.z);
    acc.w = fmaf(w, x.w, acc.w);
  }
  atomicAdd(&out[col + 0], acc.x);
  atomicAdd(&out[col + 1], acc.y);
  atomicAdd(&out[col + 2], acc.z);
  atomicAdd(&out[col + 3], acc.w);
}

}  // namespace

extern "C" void kernel_launch(void* const* d_in, const int* in_sizes, int n_in,
                              void* d_out, int out_size, void* d_ws, size_t ws_size,
                              hipStream_t stream) {
  const float* sentence = (const float*)d_in[0];
  const int* length     = (const int*)d_in[1];
  const float* ctx_p = (const float*)d_in[2];
  const float* ctx_c = (const float*)d_in[3];
  const float* ctx_h = (const float*)d_in[4];
  const float* W_s[3] = {(const float*)d_in[5],  (const float*)d_in[11], (const float*)d_in[17]};
  const float* b_s[3] = {(const float*)d_in[6],  (const float*)d_in[12], (const float*)d_in[18]};
  const float* W_c[3] = {(const float*)d_in[7],  (const float*)d_in[13], (const float*)d_in[19]};
  const float* b_c[3] = {(const float*)d_in[8],  (const float*)d_in[14], (const float*)d_in[20]};
  const float* v_[3]  = {(const float*)d_in[9],  (const float*)d_in[15], (const float*)d_in[21]};
  float* out = (float*)d_out;

  // workspace layout (bytes)
  char* ws = (char*)d_ws;
  __bf16* sentB = (__bf16*)(ws);               // 8192*1024*2   = 16777216
  __bf16* WtB   = (__bf16*)(ws + 16777216);    // 3*2048*1024*2 = 12582912
  float* ctxb   = (float*)(ws + 29360128);     // 3*2048*4      = 24576
  float* e_arr  = (float*)(ws + 29384704);     // 3*8192*4      = 98304

  // ctxb + e_arr are contiguous: one memset covers both (atomic accumulation targets)
  hipMemsetAsync(ctxb, 0, (A * 3 + S * 3) * sizeof(float), stream);

  k_prep<<<6209, 256, 0, stream>>>(sentence, sentB,
                                   W_s[0], W_s[1], W_s[2], WtB,
                                   ctx_p, ctx_c, ctx_h,
                                   W_c[0], W_c[1], W_c[2],
                                   b_s[0], b_s[1], b_s[2],
                                   b_c[0], b_c[1], b_c[2], ctxb,
                                   length, out, out_size);
  k_gemm_e<<<dim3(S / 128, A / 128, 3), 256, 0, stream>>>(sentB, WtB, ctxb,
                                                          v_[0], v_[1], v_[2], length, e_arr);
  k_out<<<S / 16, 256, 0, stream>>>(sentence, e_arr, length, out);
}

// Round 2
// 212.784 us; speedup vs baseline: 1.1013x; 1.1013x over previous
//
#include <hip/hip_runtime.h>
#include <hip/hip_bf16.h>
#include <stdint.h>

// Problem: 3x Bahdanau attention (p/c/h heads) -> averaged softmax weights -> weighted sum of sentence.
// S=8192, H2=1024, A=2048, E=768. All inputs fp32; output fp32 [1024].
// R2: 233.6us, k_gemm_e 71.5us (syncthreads-drained loop, MfmaUtil 13%).
// R3: REGRESSED k_gemm_e to 84.9us: "memory" clobber on the waitcnt asm made the compiler drain
//     vmcnt(0) before every barrier -> counted prefetch never engaged, paid 49KB LDS for nothing.
// R4: (a) template-conformant pipeline: raw __builtin_amdgcn_s_barrier + clobber-free
//         "s_waitcnt vmcnt(3)" + sched_barrier(0) fence; 3 buffers, loads waited 2 iters after
//         issue (never drain to 0 in-loop).
//     (b) BM 128->64: live blocks 720->1440 (~5.6/CU) to double latency-hiding TLP.

namespace {

constexpr int S = 8192;
constexpr int H = 1024;   // H2
constexpr int A = 2048;
constexpr int E = 768;

typedef __bf16 bf16x8 __attribute__((ext_vector_type(8)));
typedef float f32x4 __attribute__((ext_vector_type(4)));

__device__ __forceinline__ void gl_lds16(const void* g, void* l) {
  __builtin_amdgcn_global_load_lds(
      (const __attribute__((address_space(1))) void*)g,
      (__attribute__((address_space(3))) void*)l, 16, 0, 0);
}

// ---------- merged prep ----------
// [0,4096)      cvt sentence->bf16 (only rows < round_up(len,64))
// [4096,5632)   transpose W_sent fp32 [H][A] -> bf16 [A][H]
// [5632,6208)   ctxb[head][a] = ctx @ W_ctx + b_s + b_c  (atomic partials over E-chunks)
// 6208          zero out[] (replaces a memset dispatch)
__global__ __launch_bounds__(256)
void k_prep(const float* __restrict__ sentence, __bf16* __restrict__ sentB,
            const float* __restrict__ Wp, const float* __restrict__ Wc_s,
            const float* __restrict__ Wh, __bf16* __restrict__ WtB,
            const float* __restrict__ ctx_p, const float* __restrict__ ctx_c,
            const float* __restrict__ ctx_h,
            const float* __restrict__ Wcx_p, const float* __restrict__ Wcx_c,
            const float* __restrict__ Wcx_h,
            const float* __restrict__ bs_p, const float* __restrict__ bs_c,
            const float* __restrict__ bs_h,
            const float* __restrict__ bc_p, const float* __restrict__ bc_c,
            const float* __restrict__ bc_h,
            float* __restrict__ ctxb,
            const int* __restrict__ length, float* __restrict__ out, int n_out) {
  __shared__ float tile[64][65];
  int b = blockIdx.x;
  int t = threadIdx.x;

  if (b < 4096) {
    // ---- phase 1: sentence fp32 -> bf16, 8 elems/thread; 2 rows per block ----
    int len = min(max(length[0], 0), S);
    int lenp = (len + 63) & ~63;          // GEMM touches rows < round_up(len,64)
    if (b * 2 >= lenp) return;
    int g = b * 256 + t;
    const float4* s4 = (const float4*)sentence + (size_t)g * 2;
    float4 a = s4[0], c = s4[1];
    bf16x8 o;
    o[0] = (__bf16)a.x; o[1] = (__bf16)a.y; o[2] = (__bf16)a.z; o[3] = (__bf16)a.w;
    o[4] = (__bf16)c.x; o[5] = (__bf16)c.y; o[6] = (__bf16)c.z; o[7] = (__bf16)c.w;
    *((bf16x8*)sentB + g) = o;
  } else if (b < 5632) {
    // ---- phase 2: W_sent [H][A] fp32 -> Wt [A][H] bf16 ----
    int r = b - 4096;                 // 512 tiles per head
    int head = r >> 9; r &= 511;
    const float* W = head == 0 ? Wp : (head == 1 ? Wc_s : Wh);
    __bf16* dst = WtB + (size_t)head * A * H;
    int a0 = (r & 31) * 64;           // 32 a-tiles
    int k0 = (r >> 5) * 64;           // 16 k-tiles
#pragma unroll
    for (int i = 0; i < 16; ++i) {
      int idx = t + i * 256;
      int rr = idx >> 6, cc = idx & 63;
      tile[cc][rr] = W[(size_t)(k0 + rr) * A + a0 + cc];   // coalesced over cc
    }
    __syncthreads();
#pragma unroll
    for (int i = 0; i < 16; ++i) {
      int idx = t + i * 256;
      int al = idx >> 6, kl = idx & 63;
      dst[(size_t)(a0 + al) * H + k0 + kl] = (__bf16)tile[al][kl];  // coalesced over kl
    }
  } else if (b < 6208) {
    // ---- phase 3: ctxb[head][a] += chunk of ctx @ W_ctx (+bias in chunk 0) ----
    int r = b - 5632;                 // 192 blocks per head: 8 a-blocks x 24 e-chunks
    int head = r / 192; r %= 192;
    int ablk = r & 7;
    int echk = r >> 3;                // 24 chunks of 32
    const float* ctx = head == 0 ? ctx_p : (head == 1 ? ctx_c : ctx_h);
    const float* Wc  = head == 0 ? Wcx_p : (head == 1 ? Wcx_c : Wcx_h);
    int a = ablk * 256 + t;
    float s = 0.f;
    int e0 = echk * 32;
#pragma unroll 8
    for (int e = e0; e < e0 + 32; ++e) s = fmaf(ctx[e], Wc[(size_t)e * A + a], s);
    if (echk == 0) {
      const float* bs = head == 0 ? bs_p : (head == 1 ? bs_c : bs_h);
      const float* bc = head == 0 ? bc_p : (head == 1 ? bc_c : bc_h);
      s += bs[a] + bc[a];
    }
    atomicAdd(&ctxb[head * A + a], s);
  } else {
    // ---- phase 4: zero the output accumulator ----
    float4 z = {0.f, 0.f, 0.f, 0.f};
    for (int i = t; i * 4 < n_out; i += 256) ((float4*)out)[i] = z;
  }
}

// ---------- GEMM + fused tanh*v epilogue -> e[head][s] ----------
// 64x128 tile, BK=32, 3 LDS buffers, counted vmcnt(3): tile-t loads are waited 2 iterations
// after issue, so each load has ~2 compute phases to land. Raw s_barrier (no __syncthreads:
// its vmcnt(0)-drain is the R2 stall) + clobber-free waitcnt asm (a "memory" clobber makes
// the compiler drain vmcnt(0) -- the R3 regression). sched_barrier(0) after each barrier
// keeps compiler-scheduled ds_reads from hoisting across it.
__global__ __launch_bounds__(256)
void k_gemm_e(const __bf16* __restrict__ sentB, const __bf16* __restrict__ WtB,
              const float* __restrict__ ctxb,
              const float* __restrict__ v_p, const float* __restrict__ v_c,
              const float* __restrict__ v_h,
              const int* __restrict__ length, float* __restrict__ e_out) {
  int m0 = blockIdx.x * 64;
  int len = min(max(length[0], 0), S);
  if (m0 >= len) return;          // masked rows can never influence the softmax
  int n0 = blockIdx.y * 128;
  int head = blockIdx.z;
  const float* v  = head == 0 ? v_p : (head == 1 ? v_c : v_h);
  const __bf16* Wt = WtB + (size_t)head * A * H;
  const float* cb = ctxb + head * A;
  float* e_h = e_out + head * S;

  __shared__ __align__(16) __bf16 lsA[3 * 2048];   // 3 bufs x [64][32]
  __shared__ __align__(16) __bf16 lsB[3 * 4096];   // 3 bufs x [128][32]
  __shared__ float e_part[64];

  int tid = threadIdx.x;
  if (tid < 64) e_part[tid] = 0.f;   // visible well before epilogue (32 barriers intervene)

  int lane = tid & 63;
  int wave = tid >> 6;
  int wm = wave >> 1, wn = wave & 1;       // wave tile: 32 rows x 64 cols
  int quad = lane >> 4, l16 = lane & 15;

  f32x4 acc[2][4];
#pragma unroll
  for (int i = 0; i < 2; ++i)
#pragma unroll
    for (int j = 0; j < 4; ++j) acc[i][j] = (f32x4){0.f, 0.f, 0.f, 0.f};

  const __bf16* gA0 = sentB + (size_t)(m0 + (tid >> 2)) * H + ((tid & 3) * 8);
  const __bf16* gB0 = Wt + (size_t)(n0 + (tid >> 2)) * H + ((tid & 3) * 8);
  const __bf16* gB1 = gB0 + (size_t)64 * H;

  // 3 vector-mem instructions per STAGE -> vmcnt(3) == "previous tile's stage complete".
#define STAGE(bufi, kk)                                           \
  do {                                                            \
    gl_lds16(gA0 + (kk), lsA + (bufi) * 2048 + tid * 8);          \
    gl_lds16(gB0 + (kk), lsB + (bufi) * 4096 + tid * 8);          \
    gl_lds16(gB1 + (kk), lsB + (bufi) * 4096 + 2048 + tid * 8);   \
  } while (0)

#define COMPUTE(bufi)                                                                          \
  do {                                                                                         \
    bf16x8 af[2], bfv[4];                                                                      \
    _Pragma("unroll")                                                                          \
    for (int i = 0; i < 2; ++i)                                                                \
      af[i] = *(const bf16x8*)&lsA[(bufi) * 2048 + (wm * 32 + i * 16 + l16) * 32 + quad * 8];  \
    _Pragma("unroll")                                                                          \
    for (int j = 0; j < 4; ++j)                                                                \
      bfv[j] = *(const bf16x8*)&lsB[(bufi) * 4096 + (wn * 64 + j * 16 + l16) * 32 + quad * 8]; \
    _Pragma("unroll")                                                                          \
    for (int i = 0; i < 2; ++i)                                                                \
      _Pragma("unroll")                                                                        \
      for (int j = 0; j < 4; ++j)                                                              \
        acc[i][j] = __builtin_amdgcn_mfma_f32_16x16x32_bf16(af[i], bfv[j], acc[i][j], 0, 0, 0);\
  } while (0)

  // prologue: 2 tiles in flight
  STAGE(0, 0);
  STAGE(1, 32);
  int cur = 0, pf = 2;
#pragma unroll 1
  for (int t = 0; t < 31; ++t) {
    asm volatile("s_waitcnt vmcnt(3)");        // tile t landed (tile t+1's 3 stay in flight)
    __builtin_amdgcn_s_barrier();              // all waves' tile-t writes visible
    __builtin_amdgcn_sched_barrier(0);         // no ds_read hoists above this point
    if (t < 30) STAGE(pf, (t + 2) * 32);       // after barrier: WAR on buffer pf is safe
    COMPUTE(cur);
    cur = cur == 2 ? 0 : cur + 1;
    pf = pf == 2 ? 0 : pf + 1;
  }
  asm volatile("s_waitcnt vmcnt(0)");
  __builtin_amdgcn_s_barrier();
  __builtin_amdgcn_sched_barrier(0);
  COMPUTE(cur);   // tile 31

#undef STAGE
#undef COMPUTE

  float vj[4], cbj[4];
#pragma unroll
  for (int j = 0; j < 4; ++j) {
    int col = n0 + wn * 64 + j * 16 + l16;
    vj[j] = v[col];
    cbj[j] = cb[col];
  }
#pragma unroll
  for (int i = 0; i < 2; ++i) {
#pragma unroll
    for (int r = 0; r < 4; ++r) {
      float p = 0.f;
#pragma unroll
      for (int j = 0; j < 4; ++j) {
        float u = acc[i][j][r] + cbj[j];
        float ex = __expf(2.f * u);        // tanh = 1 - 2/(e^2x+1); inf-safe at both ends
        float th = 1.f - 2.f / (ex + 1.f);
        p = fmaf(th, vj[j], p);
      }
      p += __shfl_xor(p, 1);
      p += __shfl_xor(p, 2);
      p += __shfl_xor(p, 4);
      p += __shfl_xor(p, 8);
      if (l16 == 0) atomicAdd(&e_part[wm * 32 + i * 16 + quad * 4 + r], p);
    }
  }
  __syncthreads();
  if (tid < 64) atomicAdd(&e_h[m0 + tid], e_part[tid]);
}

// ---------- out[h] = sum_s w(s) * sentence[s][h]; softmax stats computed per block ----------
// Stats are redundant per block (e_arr is L2-resident) but remove the k_stats dispatch + edge.
__global__ void k_out(const float* __restrict__ sent, const float* __restrict__ e_arr,
                      const int* __restrict__ length, float* __restrict__ out) {
  int len = min(max(length[0], 0), S);
  int r0 = blockIdx.x * 16;
  if (r0 >= len) return;
  int tid = threadIdx.x;

  __shared__ float red[3][4];
  __shared__ float sstat[6];    // m0,s0,m1,s1,m2,s2
  __shared__ float wrow[16];

  // pass 1: per-head max over s < len
#pragma unroll
  for (int h = 0; h < 3; ++h) {
    const float* e_h = e_arr + h * S;
    float m = -3.4e38f;
    for (int s = tid; s < len; s += 256) m = fmaxf(m, e_h[s]);
#pragma unroll
    for (int o = 32; o >= 1; o >>= 1) m = fmaxf(m, __shfl_xor(m, o));
    if ((tid & 63) == 0) red[h][tid >> 6] = m;
  }
  __syncthreads();
  if (tid < 3) sstat[tid * 2] = fmaxf(fmaxf(red[tid][0], red[tid][1]),
                                      fmaxf(red[tid][2], red[tid][3]));
  __syncthreads();
  // pass 2: per-head sum of exp
#pragma unroll
  for (int h = 0; h < 3; ++h) {
    const float* e_h = e_arr + h * S;
    float mm = sstat[h * 2];
    float ss = 0.f;
    for (int s = tid; s < len; s += 256) ss += __expf(e_h[s] - mm);
#pragma unroll
    for (int o = 32; o >= 1; o >>= 1) ss += __shfl_xor(ss, o);
    if ((tid & 63) == 0) red[h][tid >> 6] = ss;
  }
  __syncthreads();
  if (tid < 3) sstat[tid * 2 + 1] = red[tid][0] + red[tid][1] + red[tid][2] + red[tid][3];
  __syncthreads();

  // fused weights for this block's rows (computed once, not per-thread)
  if (tid < 16 && r0 + tid < len) {
    int r = r0 + tid;
    wrow[tid] = (__expf(e_arr[r] - sstat[0]) / sstat[1] +
                 __expf(e_arr[S + r] - sstat[2]) / sstat[3] +
                 __expf(e_arr[2 * S + r] - sstat[4]) / sstat[5]) * (1.f / 3.f);
  }
  __syncthreads();

  int col = tid * 4;
  int rend = min(r0 + 16, len);
  float4 acc = {0.f, 0.f, 0.f, 0.f};
  for (int r = r0; r < rend; ++r) {
    float w = wrow[r - r0];
    float4 x = *(const float4*)(sent + (size_t)r * H + col);
    acc.x = fmaf(w, x.x, acc.x);
    acc.y = fmaf(w, x.y, acc.y);
    acc.z = fmaf(w, x.z, acc.z);
    acc.w = fmaf(w, x.w, acc.w);
  }
  atomicAdd(&out[col + 0], acc.x);
  atomicAdd(&out[col + 1], acc.y);
  atomicAdd(&out[col + 2], acc.z);
  atomicAdd(&out[col + 3], acc.w);
}

}  // namespace

extern "C" void kernel_launch(void* const* d_in, const int* in_sizes, int n_in,
                              void* d_out, int out_size, void* d_ws, size_t ws_size,
                              hipStream_t stream) {
  const float* sentence = (const float*)d_in[0];
  const int* length     = (const int*)d_in[1];
  const float* ctx_p = (const float*)d_in[2];
  const float* ctx_c = (const float*)d_in[3];
  const float* ctx_h = (const float*)d_in[4];
  const float* W_s[3] = {(const float*)d_in[5],  (const float*)d_in[11], (const float*)d_in[17]};
  const float* b_s[3] = {(const float*)d_in[6],  (const float*)d_in[12], (const float*)d_in[18]};
  const float* W_c[3] = {(const float*)d_in[7],  (const float*)d_in[13], (const float*)d_in[19]};
  const float* b_c[3] = {(const float*)d_in[8],  (const float*)d_in[14], (const float*)d_in[20]};
  const float* v_[3]  = {(const float*)d_in[9],  (const float*)d_in[15], (const float*)d_in[21]};
  float* out = (float*)d_out;

  // workspace layout (bytes)
  char* ws = (char*)d_ws;
  __bf16* sentB = (__bf16*)(ws);               // 8192*1024*2   = 16777216
  __bf16* WtB   = (__bf16*)(ws + 16777216);    // 3*2048*1024*2 = 12582912
  float* ctxb   = (float*)(ws + 29360128);     // 3*2048*4      = 24576
  float* e_arr  = (float*)(ws + 29384704);     // 3*8192*4      = 98304

  // ctxb + e_arr are contiguous: one memset covers both (atomic accumulation targets)
  hipMemsetAsync(ctxb, 0, (A * 3 + S * 3) * sizeof(float), stream);

  k_prep<<<6209, 256, 0, stream>>>(sentence, sentB,
                                   W_s[0], W_s[1], W_s[2], WtB,
                                   ctx_p, ctx_c, ctx_h,
                                   W_c[0], W_c[1], W_c[2],
                                   b_s[0], b_s[1], b_s[2],
                                   b_c[0], b_c[1], b_c[2], ctxb,
                                   length, out, out_size);
  k_gemm_e<<<dim3(S / 64, A / 128, 3), 256, 0, stream>>>(sentB, WtB, ctxb,
                                                         v_[0], v_[1], v_[2], length, e_arr);
  k_out<<<S / 16, 256, 0, stream>>>(sentence, e_arr, length, out);
}